// Round 7
// baseline (498.160 us; speedup 1.0000x reference)
//
#include <hip/hip_runtime.h>

// ---- problem constants ----
#define H_     8
#define DM_    1024
#define NQKV_  4096
#define ROWS_  16384          // SLEN*BSZ = 256*64
#define PAIRS_ 512            // BSZ*H
#define SCALE_ 0.08838834764831845f
#define LN_EPS_ 1e-5f

typedef __attribute__((ext_vector_type(8))) short short8;   // 8 bf16 (4 VGPRs)
typedef __attribute__((ext_vector_type(4))) short short4v;  // 4 bf16
typedef __attribute__((ext_vector_type(4))) float floatx4;  // MFMA accumulator

__device__ __forceinline__ float b2f(unsigned short u) {
  union { unsigned int i; float f; } v; v.i = ((unsigned int)u) << 16; return v.f;
}
__device__ __forceinline__ unsigned short f2b(float f) {
  union { unsigned int i; float f; } v; v.f = f;
  unsigned int b = v.i;
  b += 0x7FFFu + ((b >> 16) & 1u);   // round-to-nearest-even
  return (unsigned short)(b >> 16);
}

__device__ __forceinline__ void gl_lds(const unsigned short* g, unsigned short* s) {
  __builtin_amdgcn_global_load_lds(
      (const __attribute__((address_space(1))) unsigned int*)g,
      (__attribute__((address_space(3))) unsigned int*)s, 16, 0, 0);
}

// ---- async stage with XOR bank swizzle (256 threads, 128x64 tile) ----
__device__ __forceinline__ void stage_async(const unsigned short* __restrict__ g,
                                            size_t ld, unsigned short* s, int tid) {
#pragma unroll
  for (int p = 0; p < 4; ++p) {
    int idx = p * 256 + tid;
    int r = idx >> 3, j = idx & 7;
    int cg = j ^ (r & 7);
    gl_lds(g + (size_t)r * ld + cg * 8, s + (size_t)idx * 8);
  }
}
// ---- 512-thread half-tile stage with precomputed per-lane offsets ----
__device__ __forceinline__ void stage_h(const unsigned short* __restrict__ g,
                                        size_t o0, size_t o1,
                                        unsigned short* s, int lo0, int lo1) {
  gl_lds(g + o0, s + lo0);
  gl_lds(g + o1, s + lo1);
}
__device__ __forceinline__ short8 lds_frag(const unsigned short* s, int row, int cg) {
  return *(const short8*)(s + row * 64 + ((cg ^ (row & 7)) << 3));
}

// =====================================================================
// K0: fused fp32 -> bf16 convert of h, Wqkv, Wo (8 elems/thread)
// =====================================================================
__global__ __launch_bounds__(256) void cvt_all(const float* __restrict__ h,
                                               const float* __restrict__ wq,
                                               const float* __restrict__ wo,
                                               unsigned short* __restrict__ hb,
                                               unsigned short* __restrict__ wqb,
                                               unsigned short* __restrict__ wob) {
  int i = blockIdx.x * 256 + threadIdx.x;
  const float* src; unsigned short* dst; int off;
  if (i < 2097152)      { src = h;  dst = hb;  off = i; }
  else if (i < 2621440) { src = wq; dst = wqb; off = i - 2097152; }
  else                  { src = wo; dst = wob; off = i - 2621440; }
  const float4* s4 = (const float4*)(src + (size_t)off * 8);
  float4 v0 = s4[0], v1 = s4[1];
  union { short8 v; unsigned short u[8]; } pk;
  pk.u[0] = f2b(v0.x); pk.u[1] = f2b(v0.y); pk.u[2] = f2b(v0.z); pk.u[3] = f2b(v0.w);
  pk.u[4] = f2b(v1.x); pk.u[5] = f2b(v1.y); pk.u[6] = f2b(v1.z); pk.u[7] = f2b(v1.w);
  *(short8*)(dst + (size_t)off * 8) = pk.v;
}

// =====================================================================
// K1: qkv gemm, 256x128 tile, acc[4][4] (64 AGPR) -> ~120 regs/wave ->
//   16 waves/CU = 2 blocks/CU (register-limited, not LDS: round-6 showed
//   acc[8][4]=252 regs caps at 8 waves/CU no matter the LDS size).
//   Single-buffered 48KB LDS; partner block hides stage-wait (m114).
//   grid (32,64): bx -> n0=bx*128 (hh=bx>>2, part=bx&3), by -> bb.
//   8 waves 4M x 2N, per-kk frag reads (a[4]+b[4] live = 32 VGPR).
// =====================================================================
__global__ __launch_bounds__(512, 4) void qkv_gemm(const unsigned short* __restrict__ A,
                                                   const unsigned short* __restrict__ B,
                                                   unsigned short* __restrict__ QKV) {
  __shared__ alignas(16) unsigned short Sh[24576];   // As 32KB | Bs 16KB = 49152 B
  unsigned short* As = Sh;
  unsigned short* Bs = Sh + 16384;
  int tid = threadIdx.x;
  int lane = tid & 63, wid = tid >> 6;
  int wm = wid >> 1, wn = wid & 1;          // 4M x 2N wave grid
  int quad = lane >> 4, l16 = lane & 15;
  int s7 = l16 & 7;

  // XCD-contiguous bijective swizzle (2048 blocks = 8 x 256);
  // consecutive same-XCD blocks share the A-panel (L2 locality).
  int bid = blockIdx.y * 32 + blockIdx.x;
  int swz = (bid & 7) * 256 + (bid >> 3);
  int bx = swz & 31, by = swz >> 5;
  int n0 = bx * 128, hh = bx >> 2, part = bx & 3, bb = by;

  const unsigned short* AbP = A + (size_t)bb * DM_;   // row l at AbP + l*lda
  const size_t lda = (size_t)64 * DM_;
  const unsigned short* BbP = B + (size_t)n0 * DM_;

  // stage offsets: idx = p*512+tid -> r = r0+p*64, j/cg invariant in p
  int r0 = tid >> 3, jj = tid & 7;
  int cg = jj ^ (r0 & 7);
  size_t oA0 = (size_t)r0 * lda + cg * 8;   // + p*64*lda
  size_t oB0 = (size_t)r0 * DM_ + cg * 8;   // + p*64*DM_
  int lo = tid * 8;                          // + p*4096

  floatx4 acc[4][4];
#pragma unroll
  for (int i = 0; i < 4; ++i)
#pragma unroll
    for (int j = 0; j < 4; ++j)
#pragma unroll
      for (int r = 0; r < 4; ++r) acc[i][j][r] = 0.f;

  // prologue: stage tile 0
#pragma unroll
  for (int p = 0; p < 4; ++p)
    gl_lds(AbP + oA0 + (size_t)p * 64 * lda, As + lo + p * 4096);
#pragma unroll
  for (int p = 0; p < 2; ++p)
    gl_lds(BbP + oB0 + (size_t)p * 64 * DM_, Bs + lo + p * 4096);

  const unsigned short* aB0 = As + (wm * 64 + l16) * 64 + ((quad ^ s7) << 3);
  const unsigned short* aB1 = As + (wm * 64 + l16) * 64 + (((4 + quad) ^ s7) << 3);
  const unsigned short* bB0 = Bs + (wn * 64 + l16) * 64 + ((quad ^ s7) << 3);
  const unsigned short* bB1 = Bs + (wn * 64 + l16) * 64 + (((4 + quad) ^ s7) << 3);

  for (int t = 0; t < 16; ++t) {
    asm volatile("s_waitcnt vmcnt(0)" ::: "memory");
    __builtin_amdgcn_s_barrier();
    short8 a[4], b[4];
    // kk = 0
#pragma unroll
    for (int mt = 0; mt < 4; ++mt) a[mt] = *(const short8*)(aB0 + mt * 1024);
#pragma unroll
    for (int nt = 0; nt < 4; ++nt) b[nt] = *(const short8*)(bB0 + nt * 1024);
#pragma unroll
    for (int mt = 0; mt < 4; ++mt)
#pragma unroll
      for (int nt = 0; nt < 4; ++nt)
        acc[mt][nt] = __builtin_amdgcn_mfma_f32_16x16x32_bf16(a[mt], b[nt], acc[mt][nt], 0, 0, 0);
    // kk = 1
#pragma unroll
    for (int mt = 0; mt < 4; ++mt) a[mt] = *(const short8*)(aB1 + mt * 1024);
#pragma unroll
    for (int nt = 0; nt < 4; ++nt) b[nt] = *(const short8*)(bB1 + nt * 1024);
#pragma unroll
    for (int mt = 0; mt < 4; ++mt)
#pragma unroll
      for (int nt = 0; nt < 4; ++nt)
        acc[mt][nt] = __builtin_amdgcn_mfma_f32_16x16x32_bf16(a[mt], b[nt], acc[mt][nt], 0, 0, 0);
    __syncthreads();                       // all reads of tile t done
    if (t < 15) {
      size_t kn = (size_t)(t + 1) * 64;
#pragma unroll
      for (int p = 0; p < 4; ++p)
        gl_lds(AbP + kn + oA0 + (size_t)p * 64 * lda, As + lo + p * 4096);
#pragma unroll
      for (int p = 0; p < 2; ++p)
        gl_lds(BbP + kn + oB0 + (size_t)p * 64 * DM_, Bs + lo + p * 4096);
    }
  }

  // ================= epilogue =================
  __syncthreads();
  int c = tid & 15, g = tid >> 4;          // c 0..15, g 0..31
  if (part < 3) {
    // phi: elu+1; row-sum across wn pair via LDS partial exchange
    float rsum[4][4];
#pragma unroll
    for (int mt = 0; mt < 4; ++mt)
#pragma unroll
      for (int r = 0; r < 4; ++r) rsum[mt][r] = 0.f;
#pragma unroll
    for (int mt = 0; mt < 4; ++mt)
#pragma unroll
      for (int nt = 0; nt < 4; ++nt)
#pragma unroll
        for (int r = 0; r < 4; ++r) {
          float x = acc[mt][nt][r];
          float f = x > 0.f ? x + 1.f : __expf(x);
          acc[mt][nt][r] = f;
          rsum[mt][r] += f;
        }
#pragma unroll
    for (int off = 1; off < 16; off <<= 1)
#pragma unroll
      for (int mt = 0; mt < 4; ++mt)
#pragma unroll
        for (int r = 0; r < 4; ++r)
          rsum[mt][r] += __shfl_xor(rsum[mt][r], off);
    float* Pf = (float*)Sh;               // [256][2] partials = 2KB
    if (l16 == 0) {
#pragma unroll
      for (int mt = 0; mt < 4; ++mt)
#pragma unroll
        for (int r = 0; r < 4; ++r)
          Pf[(wm * 64 + mt * 16 + quad * 4 + r) * 2 + wn] = rsum[mt][r];
    }
    __syncthreads();
    float inv[4][4];
#pragma unroll
    for (int mt = 0; mt < 4; ++mt)
#pragma unroll
      for (int r = 0; r < 4; ++r)
        inv[mt][r] = 1.f / (rsum[mt][r] + Pf[(wm * 64 + mt * 16 + quad * 4 + r) * 2 + (wn ^ 1)]);
    __syncthreads();
    // stage+store two 128-row halves through T[128][136]
    unsigned short* P = QKV + (size_t)part * 16777216 + (size_t)(bb * 8 + hh) * 32768;
#pragma unroll
    for (int hf = 0; hf < 2; ++hf) {
      if ((wm >> 1) == hf) {
#pragma unroll
        for (int mt = 0; mt < 4; ++mt)
#pragma unroll
          for (int nt = 0; nt < 4; ++nt)
#pragma unroll
            for (int r = 0; r < 4; ++r) {
              int row = (wm & 1) * 64 + mt * 16 + quad * 4 + r;
              int col = wn * 64 + nt * 16 + l16;
              Sh[row * 136 + col] = f2b(acc[mt][nt][r] * inv[mt][r]);
            }
      }
      __syncthreads();
#pragma unroll
      for (int j = 0; j < 4; ++j) {
        int row = j * 32 + g;
        *(short8*)(P + (size_t)(hf * 128 + row) * 128 + c * 8) =
            *(const short8*)(Sh + row * 136 + c * 8);
      }
      __syncthreads();
    }
  } else {
    // V: transpose T[d][l], two 128-col l-halves
    unsigned short* Vt = QKV + (size_t)3 * 16777216 + (size_t)(bb * 8 + hh) * 32768;
#pragma unroll
    for (int hf = 0; hf < 2; ++hf) {
      if ((wm >> 1) == hf) {
#pragma unroll
        for (int mt = 0; mt < 4; ++mt)
#pragma unroll
          for (int nt = 0; nt < 4; ++nt)
#pragma unroll
            for (int r = 0; r < 4; ++r) {
              int d = wn * 64 + nt * 16 + l16;
              int l = (wm & 1) * 64 + mt * 16 + quad * 4 + r;
              Sh[d * 136 + l] = f2b(acc[mt][nt][r]);
            }
      }
      __syncthreads();
#pragma unroll
      for (int j = 0; j < 4; ++j) {
        int d = j * 32 + g;
        *(short8*)(Vt + (size_t)d * 256 + hf * 128 + c * 8) =
            *(const short8*)(Sh + d * 136 + c * 8);
      }
      __syncthreads();
    }
  }
}

// =====================================================================
// Shared 256x256 4-phase double-buffered K-loop macro (wo_gemm).
// =====================================================================
#define TILE_BODY(T, BUF, OBUF)                                                \
  {                                                                            \
    unsigned short* SB = (BUF) + 16384;                                        \
    const unsigned short* aA0 = (BUF) + (wm * 128 + l16) * 64 + ((quad ^ s7) << 3); \
    const unsigned short* aA1 = (BUF) + (wm * 128 + l16) * 64 + (((4 + quad) ^ s7) << 3); \
    const unsigned short* bA0 = SB + (wn * 64 + l16) * 64 + ((quad ^ s7) << 3);\
    const unsigned short* bA1 = SB + (wn * 64 + l16) * 64 + (((4 + quad) ^ s7) << 3); \
    short8 a[8], b[4];                                                         \
    if ((T) < 15) {                                                            \
      size_t kn = (size_t)((T) + 1) * 64;                                      \
      stage_h(BbP + kn,  oB0, oB1, (OBUF) + 16384, lo0, lo1);                  \
      stage_h(BbHP + kn, oB0, oB1, (OBUF) + 24576, lo0, lo1);                  \
    }                                                                          \
    _Pragma("unroll")                                                          \
    for (int mt = 0; mt < 4; ++mt) {                                           \
      a[mt * 2 + 0] = *(const short8*)(aA0 + mt * 1024);                       \
      a[mt * 2 + 1] = *(const short8*)(aA1 + mt * 1024);                       \
    }                                                                          \
    _Pragma("unroll")                                                          \
    for (int nt = 0; nt < 2; ++nt) {                                           \
      b[nt * 2 + 0] = *(const short8*)(bA0 + nt * 1024);                       \
      b[nt * 2 + 1] = *(const short8*)(bA1 + nt * 1024);                       \
    }                                                                          \
    __builtin_amdgcn_sched_barrier(0);                                         \
    __builtin_amdgcn_s_barrier();                                              \
    __builtin_amdgcn_s_setprio(1);                                             \
    _Pragma("unroll")                                                          \
    for (int kk = 0; kk < 2; ++kk)                                             \
      _Pragma("unroll")                                                        \
      for (int m = 0; m < 4; ++m)                                              \
        _Pragma("unroll")                                                      \
        for (int n = 0; n < 2; ++n)                                            \
          acc[m][n] = __builtin_amdgcn_mfma_f32_16x16x32_bf16(a[m * 2 + kk], b[n * 2 + kk], acc[m][n], 0, 0, 0); \
    __builtin_amdgcn_s_setprio(0);                                             \
    __builtin_amdgcn_s_barrier();                                              \
    _Pragma("unroll")                                                          \
    for (int nt = 0; nt < 2; ++nt) {                                           \
      b[nt * 2 + 0] = *(const short8*)(bA0 + 2048 + nt * 1024);                \
      b[nt * 2 + 1] = *(const short8*)(bA1 + 2048 + nt * 1024);                \
    }                                                                          \
    __builtin_amdgcn_sched_barrier(0);                                         \
    __builtin_amdgcn_s_barrier();                                              \
    __builtin_amdgcn_s_setprio(1);                                             \
    _Pragma("unroll")                                                          \
    for (int kk = 0; kk < 2; ++kk)                                             \
      _Pragma("unroll")                                                        \
      for (int m = 0; m < 4; ++m)                                              \
        _Pragma("unroll")                                                      \
        for (int n = 0; n < 2; ++n)                                            \
          acc[m][2 + n] = __builtin_amdgcn_mfma_f32_16x16x32_bf16(a[m * 2 + kk], b[n * 2 + kk], acc[m][2 + n], 0, 0, 0); \
    __builtin_amdgcn_s_setprio(0);                                             \
    __builtin_amdgcn_s_barrier();                                              \
    _Pragma("unroll")                                                          \
    for (int mt = 0; mt < 4; ++mt) {                                           \
      a[mt * 2 + 0] = *(const short8*)(aA0 + 4096 + mt * 1024);                \
      a[mt * 2 + 1] = *(const short8*)(aA1 + 4096 + mt * 1024);                \
    }                                                                          \
    __builtin_amdgcn_sched_barrier(0);                                         \
    __builtin_amdgcn_s_barrier();                                              \
    __builtin_amdgcn_s_setprio(1);                                             \
    _Pragma("unroll")                                                          \
    for (int kk = 0; kk < 2; ++kk)                                             \
      _Pragma("unroll")                                                        \
      for (int m = 0; m < 4; ++m)                                              \
        _Pragma("unroll")                                                      \
        for (int n = 0; n < 2; ++n)                                            \
          acc[4 + m][2 + n] = __builtin_amdgcn_mfma_f32_16x16x32_bf16(a[m * 2 + kk], b[n * 2 + kk], acc[4 + m][2 + n], 0, 0, 0); \
    __builtin_amdgcn_s_setprio(0);                                             \
    __builtin_amdgcn_s_barrier();                                              \
    if ((T) < 14) {                                                            \
      size_t kt2 = (size_t)((T) + 2) * 64;                                     \
      stage_h(AbP + kt2,  oA0, oA1, (BUF),        lo0, lo1);                   \
      stage_h(AbHP + kt2, oA0, oA1, (BUF) + 8192, lo0, lo1);                   \
    }                                                                          \
    _Pragma("unroll")                                                          \
    for (int nt = 0; nt < 2; ++nt) {                                           \
      b[nt * 2 + 0] = *(const short8*)(bA0 + nt * 1024);                       \
      b[nt * 2 + 1] = *(const short8*)(bA1 + nt * 1024);                       \
    }                                                                          \
    __builtin_amdgcn_sched_barrier(0);                                         \
    __builtin_amdgcn_s_barrier();                                              \
    __builtin_amdgcn_s_setprio(1);                                             \
    _Pragma("unroll")                                                          \
    for (int kk = 0; kk < 2; ++kk)                                             \
      _Pragma("unroll")                                                        \
      for (int m = 0; m < 4; ++m)                                              \
        _Pragma("unroll")                                                      \
        for (int n = 0; n < 2; ++n)                                            \
          acc[4 + m][n] = __builtin_amdgcn_mfma_f32_16x16x32_bf16(a[m * 2 + kk], b[n * 2 + kk], acc[4 + m][n], 0, 0, 0); \
    __builtin_amdgcn_s_setprio(0);                                             \
    if ((T) < 14) { asm volatile("s_waitcnt vmcnt(4)" ::: "memory"); }         \
    else          { asm volatile("s_waitcnt vmcnt(0)" ::: "memory"); }         \
    __builtin_amdgcn_s_barrier();                                              \
  }

// =====================================================================
// K3: combined masked scores.  grid (3, 1, 512); full-line S stores.
// =====================================================================
__global__ __launch_bounds__(256) void scores_kernel(const unsigned short* __restrict__ QKV,
                                                     const float* __restrict__ pi0,
                                                     unsigned short* __restrict__ S) {
  __shared__ alignas(16) unsigned short Sh[24576];
  __shared__ float pis[128];
  unsigned short* As  = Sh;
  unsigned short* Bs1 = Sh + 8192;
  unsigned short* Bs2 = Sh + 16384;
  int p = blockIdx.z;
  int hh = p & 7;
  int tid = threadIdx.x;
  int lane = tid & 63, wid = tid >> 6;
  int wm = wid >> 1, wn = wid & 1;
  int quad = lane >> 4, l16 = lane & 15;
  int tix = blockIdx.x;
  int m0 = (tix >= 1) ? 128 : 0;
  int n0 = (tix == 2) ? 128 : 0;
  if (tid < 128) {
    float pv = pi0[hh * 256 + m0 + tid];
    pis[tid] = fminf(fmaxf(pv, 0.f), 1.f);
  }
  const unsigned short* Qb  = QKV + (size_t)p * 32768 + (size_t)m0 * 128;
  const unsigned short* K1b = QKV + 16777216     + (size_t)p * 32768 + (size_t)n0 * 128;
  const unsigned short* K2b = QKV + 2 * 16777216 + (size_t)p * 32768 + (size_t)n0 * 128;

  floatx4 acc1[4][4], acc2[4][4];
#pragma unroll
  for (int i = 0; i < 4; ++i)
#pragma unroll
    for (int j = 0; j < 4; ++j)
#pragma unroll
      for (int r = 0; r < 4; ++r) { acc1[i][j][r] = 0.f; acc2[i][j][r] = 0.f; }

  for (int kt = 0; kt < 128; kt += 64) {
    stage_async(Qb + kt, 128, As, tid);
    stage_async(K1b + kt, 128, Bs1, tid);
    stage_async(K2b + kt, 128, Bs2, tid);
    __syncthreads();
#pragma unroll
    for (int kk = 0; kk < 2; ++kk) {
      short8 af[4], b1[4], b2v[4];
#pragma unroll
      for (int mt = 0; mt < 4; ++mt)
        af[mt] = lds_frag(As, wm * 64 + mt * 16 + l16, kk * 4 + quad);
#pragma unroll
      for (int nt = 0; nt < 4; ++nt) {
        b1[nt]  = lds_frag(Bs1, wn * 64 + nt * 16 + l16, kk * 4 + quad);
        b2v[nt] = lds_frag(Bs2, wn * 64 + nt * 16 + l16, kk * 4 + quad);
      }
#pragma unroll
      for (int mt = 0; mt < 4; ++mt)
#pragma unroll
        for (int nt = 0; nt < 4; ++nt) {
          acc1[mt][nt] = __builtin_amdgcn_mfma_f32_16x16x32_bf16(af[mt], b1[nt],  acc1[mt][nt], 0, 0, 0);
          acc2[mt][nt] = __builtin_amdgcn_mfma_f32_16x16x32_bf16(af[mt], b2v[nt], acc2[mt][nt], 0, 0, 0);
        }
    }
    __syncthreads();
  }
#pragma unroll
  for (int mt = 0; mt < 4; ++mt)
#pragma unroll
    for (int nt = 0; nt < 4; ++nt)
#pragma unroll
      for (int r = 0; r < 4; ++r) {
        int tl = wm * 64 + mt * 16 + quad * 4 + r;
        int sl = wn * 64 + nt * 16 + l16;
        float pv = pis[tl];
        float v = (n0 + sl <= m0 + tl) ? (pv * acc1[mt][nt][r] + (1.f - pv) * acc2[mt][nt][r]) : 0.f;
        Sh[tl * 136 + sl] = f2b(v);
      }
  __syncthreads();
  int c = tid & 15, g = tid >> 4;
#pragma unroll
  for (int j = 0; j < 8; ++j) {
    int r = j * 16 + g;
    size_t gb = (size_t)p * 65536 + (size_t)(m0 + r) * 256 + n0 + c * 8;
    *(short8*)(S + gb) = *(const short8*)(Sh + r * 136 + c * 8);
  }
}

// =====================================================================
// K4: O = SCALE * S @ V -> LO; full-line stores.  grid (1,2,512)
// =====================================================================
__global__ __launch_bounds__(256, 4) void pv_kernel(const unsigned short* __restrict__ S,
                                                    const unsigned short* __restrict__ Vt,
                                                    unsigned short* __restrict__ LO) {
  __shared__ alignas(16) unsigned short Sh[17408];
  unsigned short* As = Sh;
  unsigned short* Bs = Sh + 8192;
  int p = blockIdx.z;
  int b = p >> 3, hh = p & 7;
  int tid = threadIdx.x;
  int lane = tid & 63, wid = tid >> 6;
  int wm = wid >> 1, wn = wid & 1;
  int quad = lane >> 4, l16 = lane & 15;
  int m0 = blockIdx.y * 128;
  int kEnd = (blockIdx.y == 0) ? 128 : 256;
  const unsigned short* Ab = S  + (size_t)p * 65536 + (size_t)m0 * 256;
  const unsigned short* Bb = Vt + (size_t)p * 32768;

  floatx4 acc[4][4];
#pragma unroll
  for (int i = 0; i < 4; ++i)
#pragma unroll
    for (int j = 0; j < 4; ++j)
#pragma unroll
      for (int r = 0; r < 4; ++r) acc[i][j][r] = 0.f;

  for (int kt = 0; kt < kEnd; kt += 64) {
    stage_async(Ab + kt, 256, As, tid);
    stage_async(Bb + kt, 256, Bs, tid);
    __syncthreads();
#pragma unroll
    for (int kk = 0; kk < 2; ++kk) {
      short8 af[4], bfv[4];
#pragma unroll
      for (int mt = 0; mt < 4; ++mt)
        af[mt] = lds_frag(As, wm * 64 + mt * 16 + l16, kk * 4 + quad);
#pragma unroll
      for (int nt = 0; nt < 4; ++nt)
        bfv[nt] = lds_frag(Bs, wn * 64 + nt * 16 + l16, kk * 4 + quad);
#pragma unroll
      for (int mt = 0; mt < 4; ++mt)
#pragma unroll
        for (int nt = 0; nt < 4; ++nt)
          acc[mt][nt] = __builtin_amdgcn_mfma_f32_16x16x32_bf16(af[mt], bfv[nt], acc[mt][nt], 0, 0, 0);
    }
    __syncthreads();
  }
#pragma unroll
  for (int mt = 0; mt < 4; ++mt)
#pragma unroll
    for (int nt = 0; nt < 4; ++nt)
#pragma unroll
      for (int r = 0; r < 4; ++r) {
        int tl = wm * 64 + mt * 16 + quad * 4 + r;
        int d = wn * 64 + nt * 16 + l16;
        Sh[tl * 136 + d] = f2b(SCALE_ * acc[mt][nt][r]);
      }
  __syncthreads();
  int c = tid & 15, g = tid >> 4;
#pragma unroll
  for (int j = 0; j < 8; ++j) {
    int r = j * 16 + g;
    int t = m0 + r;
    size_t gb = ((size_t)t * 64 + b) * 1024 + hh * 128 + c * 8;
    *(short8*)(LO + gb) = *(const short8*)(Sh + r * 136 + c * 8);
  }
}

// =====================================================================
// K5: attn_out = LO @ Wo^T (bf16 out) — 256x256 4-phase dbuf, 1 round.
// =====================================================================
__global__ __launch_bounds__(512, 1) void wo_gemm(const unsigned short* __restrict__ A,
                                                  const unsigned short* __restrict__ B,
                                                  unsigned short* __restrict__ attn) {
  __shared__ alignas(16) unsigned short Sh[65536];
  int tid = threadIdx.x;
  int lane = tid & 63, wid = tid >> 6;
  int wm = wid >> 2, wn = wid & 3;
  int quad = lane >> 4, l16 = lane & 15;
  int s7 = l16 & 7;

  int bid = blockIdx.y * 4 + blockIdx.x;
  int swz = (bid & 7) * 32 + (bid >> 3);
  int bx = swz & 3, by = swz >> 2;
  int n0 = bx * 256, m0 = by * 256;

  const unsigned short* AbP = A + (size_t)m0 * DM_;
  const unsigned short* AbHP = AbP + (size_t)128 * DM_;
  const unsigned short* BbP = B + (size_t)n0 * DM_;
  const unsigned short* BbHP = BbP + (size_t)128 * DM_;

  int r0 = tid >> 3, jj = tid & 7;
  int cg = jj ^ (r0 & 7);
  size_t oA0 = (size_t)r0 * DM_ + cg * 8;
  size_t oA1 = (size_t)(r0 + 64) * DM_ + cg * 8;
  size_t oB0 = oA0, oB1 = oA1;
  int lo0 = tid * 8, lo1 = 4096 + tid * 8;

  floatx4 acc[8][4];
#pragma unroll
  for (int i = 0; i < 8; ++i)
#pragma unroll
    for (int j = 0; j < 4; ++j)
#pragma unroll
      for (int r = 0; r < 4; ++r) acc[i][j][r] = 0.f;

  stage_h(AbP,        oA0, oA1, Sh,         lo0, lo1);
  stage_h(AbHP,       oA0, oA1, Sh + 8192,  lo0, lo1);
  stage_h(BbP,        oB0, oB1, Sh + 16384, lo0, lo1);
  stage_h(BbHP,       oB0, oB1, Sh + 24576, lo0, lo1);
  stage_h(AbP + 64,   oA0, oA1, Sh + 32768, lo0, lo1);
  stage_h(AbHP + 64,  oA0, oA1, Sh + 40960, lo0, lo1);
  asm volatile("s_waitcnt vmcnt(4)" ::: "memory");
  __builtin_amdgcn_s_barrier();

  for (int t = 0; t < 16; t += 2) {
    TILE_BODY(t,     Sh,         Sh + 32768)
    TILE_BODY(t + 1, Sh + 32768, Sh)
  }

  __syncthreads();
#pragma unroll
  for (int hq = 0; hq < 2; ++hq) {
    if ((wn >> 1) == hq) {
#pragma unroll
      for (int mt = 0; mt < 8; ++mt)
#pragma unroll
        for (int nt = 0; nt < 4; ++nt)
#pragma unroll
          for (int r = 0; r < 4; ++r) {
            int row = wm * 128 + mt * 16 + quad * 4 + r;
            int col = (wn & 1) * 64 + nt * 16 + l16;
            Sh[row * 136 + col] = f2b(acc[mt][nt][r]);
          }
    }
    __syncthreads();
    int c = tid & 15, g = tid >> 4;
#pragma unroll
    for (int j = 0; j < 8; ++j) {
      int row = j * 32 + g;
      *(short8*)(attn + (size_t)(m0 + row) * DM_ + n0 + hq * 128 + c * 8) =
          *(const short8*)(Sh + row * 136 + c * 8);
    }
    __syncthreads();
  }
}

// =====================================================================
// K6: fused residual + LayerNorm: out = LN(h + attn_bf16).  1 block/row.
// =====================================================================
__global__ __launch_bounds__(256) void ln_res(const unsigned short* __restrict__ attn,
                                              const float* __restrict__ hin,
                                              const float* __restrict__ gamma,
                                              const float* __restrict__ beta,
                                              float* __restrict__ out) {
  int row = blockIdx.x;
  int tid = threadIdx.x;
  const unsigned short* ap = attn + (size_t)row * DM_ + tid * 4;
  const float* hp = hin + (size_t)row * DM_ + tid * 4;
  short4v av = *(const short4v*)ap;
  float4 hv = *(const float4*)hp;
  float x[4];
  x[0] = hv.x + b2f((unsigned short)av[0]);
  x[1] = hv.y + b2f((unsigned short)av[1]);
  x[2] = hv.z + b2f((unsigned short)av[2]);
  x[3] = hv.w + b2f((unsigned short)av[3]);
  float s  = x[0] + x[1] + x[2] + x[3];
  float ss = x[0] * x[0] + x[1] * x[1] + x[2] * x[2] + x[3] * x[3];
#pragma unroll
  for (int off = 32; off; off >>= 1) {
    s  += __shfl_down(s, off);
    ss += __shfl_down(ss, off);
  }
  __shared__ float rs[4], rss[4];
  int wv = tid >> 6, lane = tid & 63;
  if (lane == 0) { rs[wv] = s; rss[wv] = ss; }
  __syncthreads();
  float St  = rs[0] + rs[1] + rs[2] + rs[3];
  float SSt = rss[0] + rss[1] + rss[2] + rss[3];
  float mu = St * (1.f / DM_);
  float var = SSt * (1.f / DM_) - mu * mu;
  float rstd = rsqrtf(var + LN_EPS_);
  float4 o;
#pragma unroll
  for (int j = 0; j < 4; ++j) {
    int c = tid * 4 + j;
    (&o.x)[j] = gamma[c] * (x[j] - mu) * rstd + beta[c];
  }
  *(float4*)(out + (size_t)row * DM_ + tid * 4) = o;
}

// =====================================================================
extern "C" void kernel_launch(void* const* d_in, const int* in_sizes, int n_in,
                              void* d_out, int out_size, void* d_ws, size_t ws_size,
                              hipStream_t stream) {
  const float* h     = (const float*)d_in[0];
  const float* Wqkv  = (const float*)d_in[1];
  const float* Wo    = (const float*)d_in[2];
  const float* pi0   = (const float*)d_in[3];
  const float* gamma = (const float*)d_in[4];
  const float* beta  = (const float*)d_in[5];
  char* ws = (char*)d_ws;

  unsigned short* QKV   = (unsigned short*)ws;
  unsigned short* Sbuf  = (unsigned short*)(ws + 134217728ull);
  unsigned short* hb    = (unsigned short*)(ws + 134217728ull);   // dead after qkv_gemm
  unsigned short* Wqkvb = (unsigned short*)(ws + 167772160ull);   // dead after qkv_gemm
  unsigned short* Wob   = (unsigned short*)(ws + 201326592ull);
  unsigned short* LO    = (unsigned short*)ws;                    // overwrites q-part (dead)
  unsigned short* attn  = (unsigned short*)(ws + 134217728ull);   // overwrites Sbuf (dead after pv)
  float* X = (float*)d_out;

  dim3 blk(256);
  cvt_all<<<dim3(10752), blk, 0, stream>>>(h, Wqkv, Wo, hb, Wqkvb, Wob);
  qkv_gemm<<<dim3(32, 64, 1), dim3(512), 0, stream>>>(hb, Wqkvb, QKV);
  scores_kernel<<<dim3(3, 1, PAIRS_), blk, 0, stream>>>(QKV, pi0, Sbuf);
  pv_kernel<<<dim3(1, 2, PAIRS_), blk, 0, stream>>>(Sbuf, QKV + (size_t)3 * 16777216, LO);
  wo_gemm<<<dim3(4, 64, 1), dim3(512), 0, stream>>>(LO, Wob, attn);
  ln_res<<<dim3(ROWS_, 1, 1), blk, 0, stream>>>(attn, h, gamma, beta, X);
}

// Round 8
// 419.668 us; speedup vs baseline: 1.1870x; 1.1870x over previous
//
#include <hip/hip_runtime.h>

// ---- problem constants ----
#define H_     8
#define DM_    1024
#define NQKV_  4096
#define ROWS_  16384          // SLEN*BSZ = 256*64
#define PAIRS_ 512            // BSZ*H
#define SCALE_ 0.08838834764831845f
#define LN_EPS_ 1e-5f

typedef __attribute__((ext_vector_type(8))) short short8;   // 8 bf16 (4 VGPRs)
typedef __attribute__((ext_vector_type(4))) short short4v;  // 4 bf16
typedef __attribute__((ext_vector_type(4))) float floatx4;  // MFMA accumulator

__device__ __forceinline__ float b2f(unsigned short u) {
  union { unsigned int i; float f; } v; v.i = ((unsigned int)u) << 16; return v.f;
}
__device__ __forceinline__ unsigned short f2b(float f) {
  union { unsigned int i; float f; } v; v.f = f;
  unsigned int b = v.i;
  b += 0x7FFFu + ((b >> 16) & 1u);   // round-to-nearest-even
  return (unsigned short)(b >> 16);
}

__device__ __forceinline__ void gl_lds(const unsigned short* g, unsigned short* s) {
  __builtin_amdgcn_global_load_lds(
      (const __attribute__((address_space(1))) unsigned int*)g,
      (__attribute__((address_space(3))) unsigned int*)s, 16, 0, 0);
}

// ---- async stage with XOR bank swizzle (256 threads, 128x64 tile) ----
__device__ __forceinline__ void stage_async(const unsigned short* __restrict__ g,
                                            size_t ld, unsigned short* s, int tid) {
#pragma unroll
  for (int p = 0; p < 4; ++p) {
    int idx = p * 256 + tid;
    int r = idx >> 3, j = idx & 7;
    int cg = j ^ (r & 7);
    gl_lds(g + (size_t)r * ld + cg * 8, s + (size_t)idx * 8);
  }
}
// ---- 512-thread half-tile stage with precomputed per-lane offsets ----
__device__ __forceinline__ void stage_h(const unsigned short* __restrict__ g,
                                        size_t o0, size_t o1,
                                        unsigned short* s, int lo0, int lo1) {
  gl_lds(g + o0, s + lo0);
  gl_lds(g + o1, s + lo1);
}
__device__ __forceinline__ short8 lds_frag(const unsigned short* s, int row, int cg) {
  return *(const short8*)(s + row * 64 + ((cg ^ (row & 7)) << 3));
}

// =====================================================================
// K0: fused fp32 -> bf16 convert of h, Wqkv, Wo (8 elems/thread)
// =====================================================================
__global__ __launch_bounds__(256) void cvt_all(const float* __restrict__ h,
                                               const float* __restrict__ wq,
                                               const float* __restrict__ wo,
                                               unsigned short* __restrict__ hb,
                                               unsigned short* __restrict__ wqb,
                                               unsigned short* __restrict__ wob) {
  int i = blockIdx.x * 256 + threadIdx.x;
  const float* src; unsigned short* dst; int off;
  if (i < 2097152)      { src = h;  dst = hb;  off = i; }
  else if (i < 2621440) { src = wq; dst = wqb; off = i - 2097152; }
  else                  { src = wo; dst = wob; off = i - 2621440; }
  const float4* s4 = (const float4*)(src + (size_t)off * 8);
  float4 v0 = s4[0], v1 = s4[1];
  union { short8 v; unsigned short u[8]; } pk;
  pk.u[0] = f2b(v0.x); pk.u[1] = f2b(v0.y); pk.u[2] = f2b(v0.z); pk.u[3] = f2b(v0.w);
  pk.u[4] = f2b(v1.x); pk.u[5] = f2b(v1.y); pk.u[6] = f2b(v1.z); pk.u[7] = f2b(v1.w);
  *(short8*)(dst + (size_t)off * 8) = pk.v;
}

// =====================================================================
// K1: qkv gemm, 256x256 tile (keeps the 285MB traffic floor), 1024
//   threads = 16 waves (4M x 4N), acc[4][4] = 64 AGPR -> ~116 regs/wave
//   -> 16 waves/CU = 4 waves/SIMD (vs 2 for the 8-wave acc[8][4] form).
//   Round-7 proved registers (not LDS) cap occupancy; rounds 4/7 proved
//   smaller tiles blow up HBM traffic.  This keeps the tile and halves
//   the per-wave footprint: read-burst <-> MFMA overlap comes from
//   4-way wave interleave per SIMD inside each barrier section (m114).
//   Double-buffered 128KB LDS, counted vmcnt(4) at tile top (stage
//   issued a full tile earlier -> wait ~free), raw s_barrier at end.
// =====================================================================
__global__ __launch_bounds__(1024, 4) void qkv_gemm(const unsigned short* __restrict__ A,
                                                    const unsigned short* __restrict__ B,
                                                    unsigned short* __restrict__ QKV) {
  __shared__ alignas(16) unsigned short Sh[65536];   // 2 bufs x (A 32KB | B 32KB)
  int tid = threadIdx.x;
  int lane = tid & 63, wid = tid >> 6;
  int wm = wid >> 2, wn = wid & 3;          // 4M x 4N wave grid, wave owns 64x64
  int quad = lane >> 4, l16 = lane & 15;
  int s7 = l16 & 7;

  // XCD-contiguous block swizzle (1024 blocks, bijective: 8 x 128)
  int bid = blockIdx.y * 16 + blockIdx.x;
  int swz = (bid & 7) * 128 + (bid >> 3);
  int bx = swz & 15, by = swz >> 4;
  int n0 = bx * 256, hh = bx >> 1, part0 = (bx & 1) * 2, bb = by;

  const unsigned short* AbP = A + (size_t)bb * DM_;   // row l at AbP + l*lda
  const size_t lda = (size_t)64 * DM_;
  const unsigned short* BbP = B + (size_t)n0 * DM_;

  // stage offsets: idx = p*1024 + tid, r = (tid>>3) + p*128, j = tid&7
  int r0 = tid >> 3, jj = tid & 7;
  int cg = jj ^ (r0 & 7);
  size_t oA = (size_t)r0 * lda + cg * 8;    // + p*128*lda
  size_t oB = (size_t)r0 * DM_ + cg * 8;    // + p*128*DM_
  int lo = tid * 8;                          // + p*8192

  floatx4 acc[4][4];
#pragma unroll
  for (int i = 0; i < 4; ++i)
#pragma unroll
    for (int j = 0; j < 4; ++j)
#pragma unroll
      for (int r = 0; r < 4; ++r) acc[i][j][r] = 0.f;

#define QSTAGE(KT, SA)                                                         \
  gl_lds(AbP + (KT) + oA,                     (SA) + lo);                      \
  gl_lds(AbP + (KT) + oA + (size_t)128 * lda, (SA) + 8192 + lo);               \
  gl_lds(BbP + (KT) + oB,                     (SA) + 16384 + lo);              \
  gl_lds(BbP + (KT) + oB + (size_t)128 * DM_, (SA) + 24576 + lo);

  QSTAGE(0, Sh)

  for (int t = 0; t < 16; ++t) {
    unsigned short* SA = Sh + (t & 1) * 32768;
    if (t < 15) { QSTAGE((size_t)(t + 1) * 64, Sh + ((t + 1) & 1) * 32768) }
    if (t < 15) { asm volatile("s_waitcnt vmcnt(4)" ::: "memory"); }   // tile t resident; t+1 in flight
    else        { asm volatile("s_waitcnt vmcnt(0)" ::: "memory"); }
    __builtin_amdgcn_s_barrier();
    const unsigned short* aB0 = SA + (wm * 64 + l16) * 64 + ((quad ^ s7) << 3);
    const unsigned short* aB1 = SA + (wm * 64 + l16) * 64 + (((4 + quad) ^ s7) << 3);
    const unsigned short* bB0 = SA + 16384 + (wn * 64 + l16) * 64 + ((quad ^ s7) << 3);
    const unsigned short* bB1 = SA + 16384 + (wn * 64 + l16) * 64 + (((4 + quad) ^ s7) << 3);
    short8 a[4], b[4];
    // kk = 0
#pragma unroll
    for (int mt = 0; mt < 4; ++mt) a[mt] = *(const short8*)(aB0 + mt * 1024);
#pragma unroll
    for (int nt = 0; nt < 4; ++nt) b[nt] = *(const short8*)(bB0 + nt * 1024);
#pragma unroll
    for (int mt = 0; mt < 4; ++mt)
#pragma unroll
      for (int nt = 0; nt < 4; ++nt)
        acc[mt][nt] = __builtin_amdgcn_mfma_f32_16x16x32_bf16(a[mt], b[nt], acc[mt][nt], 0, 0, 0);
    // kk = 1
#pragma unroll
    for (int mt = 0; mt < 4; ++mt) a[mt] = *(const short8*)(aB1 + mt * 1024);
#pragma unroll
    for (int nt = 0; nt < 4; ++nt) b[nt] = *(const short8*)(bB1 + nt * 1024);
#pragma unroll
    for (int mt = 0; mt < 4; ++mt)
#pragma unroll
      for (int nt = 0; nt < 4; ++nt)
        acc[mt][nt] = __builtin_amdgcn_mfma_f32_16x16x32_bf16(a[mt], b[nt], acc[mt][nt], 0, 0, 0);
    __builtin_amdgcn_s_barrier();          // reads of tile t retired in all waves
  }
#undef QSTAGE

  // ================= epilogue =================
  int c16 = tid & 15, g64 = tid >> 4;      // 0..15 / 0..63
  bool isV = (part0 + (wn >> 1)) == 3;
  float* Pf = (float*)Sh;                  // [256][4] partial row-sums = 4KB
  float rsum[4][4], inv[4][4];
  if (!isV) {
#pragma unroll
    for (int mt = 0; mt < 4; ++mt)
#pragma unroll
      for (int r = 0; r < 4; ++r) rsum[mt][r] = 0.f;
#pragma unroll
    for (int mt = 0; mt < 4; ++mt)
#pragma unroll
      for (int nt = 0; nt < 4; ++nt)
#pragma unroll
        for (int r = 0; r < 4; ++r) {
          float x = acc[mt][nt][r];
          float f = x > 0.f ? x + 1.f : __expf(x);
          acc[mt][nt][r] = f;
          rsum[mt][r] += f;
        }
#pragma unroll
    for (int off = 1; off < 16; off <<= 1)
#pragma unroll
      for (int mt = 0; mt < 4; ++mt)
#pragma unroll
        for (int r = 0; r < 4; ++r)
          rsum[mt][r] += __shfl_xor(rsum[mt][r], off);
    if (l16 == 0) {
#pragma unroll
      for (int mt = 0; mt < 4; ++mt)
#pragma unroll
        for (int r = 0; r < 4; ++r)
          Pf[(wm * 64 + mt * 16 + quad * 4 + r) * 4 + wn] = rsum[mt][r];
    }
  }
  __syncthreads();
  if (!isV) {
#pragma unroll
    for (int mt = 0; mt < 4; ++mt)
#pragma unroll
      for (int r = 0; r < 4; ++r)
        inv[mt][r] = 1.f / (rsum[mt][r] + Pf[(wm * 64 + mt * 16 + quad * 4 + r) * 4 + (wn ^ 1)]);
  }
  __syncthreads();

  // two 128-col parts, staged+stored sequentially through LDS
#pragma unroll
  for (int hq = 0; hq < 2; ++hq) {
    int part = part0 + hq;
    if ((wn >> 1) == hq) {
      if (part < 3) {
        // phi-normalized P: T[256][136]
#pragma unroll
        for (int mt = 0; mt < 4; ++mt)
#pragma unroll
          for (int nt = 0; nt < 4; ++nt)
#pragma unroll
            for (int r = 0; r < 4; ++r) {
              int row = wm * 64 + mt * 16 + quad * 4 + r;
              int col = (wn & 1) * 64 + nt * 16 + l16;
              Sh[row * 136 + col] = f2b(acc[mt][nt][r] * inv[mt][r]);
            }
      } else {
        // V transpose: T[128][264] = [d][l]
#pragma unroll
        for (int mt = 0; mt < 4; ++mt)
#pragma unroll
          for (int nt = 0; nt < 4; ++nt)
#pragma unroll
            for (int r = 0; r < 4; ++r) {
              int d = (wn & 1) * 64 + nt * 16 + l16;
              int l = wm * 64 + mt * 16 + quad * 4 + r;
              Sh[d * 264 + l] = f2b(acc[mt][nt][r]);
            }
      }
    }
    __syncthreads();
    if (part < 3) {
      unsigned short* P = QKV + (size_t)part * 16777216 + (size_t)(bb * 8 + hh) * 32768;
#pragma unroll
      for (int j = 0; j < 4; ++j) {
        int row = j * 64 + g64;
        *(short8*)(P + (size_t)row * 128 + c16 * 8) = *(const short8*)(Sh + row * 136 + c16 * 8);
      }
    } else {
      unsigned short* Vt = QKV + (size_t)3 * 16777216 + (size_t)(bb * 8 + hh) * 32768;
      int cg2 = tid & 31, g32 = tid >> 5;
#pragma unroll
      for (int j = 0; j < 4; ++j) {
        int d = j * 32 + g32;
        *(short8*)(Vt + (size_t)d * 256 + cg2 * 8) = *(const short8*)(Sh + d * 264 + cg2 * 8);
      }
    }
    __syncthreads();
  }
}

// =====================================================================
// Shared 256x256 4-phase double-buffered K-loop macro (wo_gemm).
// =====================================================================
#define TILE_BODY(T, BUF, OBUF)                                                \
  {                                                                            \
    unsigned short* SB = (BUF) + 16384;                                        \
    const unsigned short* aA0 = (BUF) + (wm * 128 + l16) * 64 + ((quad ^ s7) << 3); \
    const unsigned short* aA1 = (BUF) + (wm * 128 + l16) * 64 + (((4 + quad) ^ s7) << 3); \
    const unsigned short* bA0 = SB + (wn * 64 + l16) * 64 + ((quad ^ s7) << 3);\
    const unsigned short* bA1 = SB + (wn * 64 + l16) * 64 + (((4 + quad) ^ s7) << 3); \
    short8 a[8], b[4];                                                         \
    if ((T) < 15) {                                                            \
      size_t kn = (size_t)((T) + 1) * 64;                                      \
      stage_h(BbP + kn,  oB0, oB1, (OBUF) + 16384, lo0, lo1);                  \
      stage_h(BbHP + kn, oB0, oB1, (OBUF) + 24576, lo0, lo1);                  \
    }                                                                          \
    _Pragma("unroll")                                                          \
    for (int mt = 0; mt < 4; ++mt) {                                           \
      a[mt * 2 + 0] = *(const short8*)(aA0 + mt * 1024);                       \
      a[mt * 2 + 1] = *(const short8*)(aA1 + mt * 1024);                       \
    }                                                                          \
    _Pragma("unroll")                                                          \
    for (int nt = 0; nt < 2; ++nt) {                                           \
      b[nt * 2 + 0] = *(const short8*)(bA0 + nt * 1024);                       \
      b[nt * 2 + 1] = *(const short8*)(bA1 + nt * 1024);                       \
    }                                                                          \
    __builtin_amdgcn_sched_barrier(0);                                         \
    __builtin_amdgcn_s_barrier();                                              \
    __builtin_amdgcn_s_setprio(1);                                             \
    _Pragma("unroll")                                                          \
    for (int kk = 0; kk < 2; ++kk)                                             \
      _Pragma("unroll")                                                        \
      for (int m = 0; m < 4; ++m)                                              \
        _Pragma("unroll")                                                      \
        for (int n = 0; n < 2; ++n)                                            \
          acc[m][n] = __builtin_amdgcn_mfma_f32_16x16x32_bf16(a[m * 2 + kk], b[n * 2 + kk], acc[m][n], 0, 0, 0); \
    __builtin_amdgcn_s_setprio(0);                                             \
    __builtin_amdgcn_s_barrier();                                              \
    _Pragma("unroll")                                                          \
    for (int nt = 0; nt < 2; ++nt) {                                           \
      b[nt * 2 + 0] = *(const short8*)(bA0 + 2048 + nt * 1024);                \
      b[nt * 2 + 1] = *(const short8*)(bA1 + 2048 + nt * 1024);                \
    }                                                                          \
    __builtin_amdgcn_sched_barrier(0);                                         \
    __builtin_amdgcn_s_barrier();                                              \
    __builtin_amdgcn_s_setprio(1);                                             \
    _Pragma("unroll")                                                          \
    for (int kk = 0; kk < 2; ++kk)                                             \
      _Pragma("unroll")                                                        \
      for (int m = 0; m < 4; ++m)                                              \
        _Pragma("unroll")                                                      \
        for (int n = 0; n < 2; ++n)                                            \
          acc[m][2 + n] = __builtin_amdgcn_mfma_f32_16x16x32_bf16(a[m * 2 + kk], b[n * 2 + kk], acc[m][2 + n], 0, 0, 0); \
    __builtin_amdgcn_s_setprio(0);                                             \
    __builtin_amdgcn_s_barrier();                                              \
    _Pragma("unroll")                                                          \
    for (int mt = 0; mt < 4; ++mt) {                                           \
      a[mt * 2 + 0] = *(const short8*)(aA0 + 4096 + mt * 1024);                \
      a[mt * 2 + 1] = *(const short8*)(aA1 + 4096 + mt * 1024);                \
    }                                                                          \
    __builtin_amdgcn_sched_barrier(0);                                         \
    __builtin_amdgcn_s_barrier();                                              \
    __builtin_amdgcn_s_setprio(1);                                             \
    _Pragma("unroll")                                                          \
    for (int kk = 0; kk < 2; ++kk)                                             \
      _Pragma("unroll")                                                        \
      for (int m = 0; m < 4; ++m)                                              \
        _Pragma("unroll")                                                      \
        for (int n = 0; n < 2; ++n)                                            \
          acc[4 + m][2 + n] = __builtin_amdgcn_mfma_f32_16x16x32_bf16(a[m * 2 + kk], b[n * 2 + kk], acc[4 + m][2 + n], 0, 0, 0); \
    __builtin_amdgcn_s_setprio(0);                                             \
    __builtin_amdgcn_s_barrier();                                              \
    if ((T) < 14) {                                                            \
      size_t kt2 = (size_t)((T) + 2) * 64;                                     \
      stage_h(AbP + kt2,  oA0, oA1, (BUF),        lo0, lo1);                   \
      stage_h(AbHP + kt2, oA0, oA1, (BUF) + 8192, lo0, lo1);                   \
    }                                                                          \
    _Pragma("unroll")                                                          \
    for (int nt = 0; nt < 2; ++nt) {                                           \
      b[nt * 2 + 0] = *(const short8*)(bA0 + nt * 1024);                       \
      b[nt * 2 + 1] = *(const short8*)(bA1 + nt * 1024);                       \
    }                                                                          \
    __builtin_amdgcn_sched_barrier(0);                                         \
    __builtin_amdgcn_s_barrier();                                              \
    __builtin_amdgcn_s_setprio(1);                                             \
    _Pragma("unroll")                                                          \
    for (int kk = 0; kk < 2; ++kk)                                             \
      _Pragma("unroll")                                                        \
      for (int m = 0; m < 4; ++m)                                              \
        _Pragma("unroll")                                                      \
        for (int n = 0; n < 2; ++n)                                            \
          acc[4 + m][n] = __builtin_amdgcn_mfma_f32_16x16x32_bf16(a[m * 2 + kk], b[n * 2 + kk], acc[4 + m][n], 0, 0, 0); \
    __builtin_amdgcn_s_setprio(0);                                             \
    if ((T) < 14) { asm volatile("s_waitcnt vmcnt(4)" ::: "memory"); }         \
    else          { asm volatile("s_waitcnt vmcnt(0)" ::: "memory"); }         \
    __builtin_amdgcn_s_barrier();                                              \
  }

// =====================================================================
// K3: combined masked scores.  grid (3, 1, 512); full-line S stores.
// =====================================================================
__global__ __launch_bounds__(256) void scores_kernel(const unsigned short* __restrict__ QKV,
                                                     const float* __restrict__ pi0,
                                                     unsigned short* __restrict__ S) {
  __shared__ alignas(16) unsigned short Sh[24576];
  __shared__ float pis[128];
  unsigned short* As  = Sh;
  unsigned short* Bs1 = Sh + 8192;
  unsigned short* Bs2 = Sh + 16384;
  int p = blockIdx.z;
  int hh = p & 7;
  int tid = threadIdx.x;
  int lane = tid & 63, wid = tid >> 6;
  int wm = wid >> 1, wn = wid & 1;
  int quad = lane >> 4, l16 = lane & 15;
  int tix = blockIdx.x;
  int m0 = (tix >= 1) ? 128 : 0;
  int n0 = (tix == 2) ? 128 : 0;
  if (tid < 128) {
    float pv = pi0[hh * 256 + m0 + tid];
    pis[tid] = fminf(fmaxf(pv, 0.f), 1.f);
  }
  const unsigned short* Qb  = QKV + (size_t)p * 32768 + (size_t)m0 * 128;
  const unsigned short* K1b = QKV + 16777216     + (size_t)p * 32768 + (size_t)n0 * 128;
  const unsigned short* K2b = QKV + 2 * 16777216 + (size_t)p * 32768 + (size_t)n0 * 128;

  floatx4 acc1[4][4], acc2[4][4];
#pragma unroll
  for (int i = 0; i < 4; ++i)
#pragma unroll
    for (int j = 0; j < 4; ++j)
#pragma unroll
      for (int r = 0; r < 4; ++r) { acc1[i][j][r] = 0.f; acc2[i][j][r] = 0.f; }

  for (int kt = 0; kt < 128; kt += 64) {
    stage_async(Qb + kt, 128, As, tid);
    stage_async(K1b + kt, 128, Bs1, tid);
    stage_async(K2b + kt, 128, Bs2, tid);
    __syncthreads();
#pragma unroll
    for (int kk = 0; kk < 2; ++kk) {
      short8 af[4], b1[4], b2v[4];
#pragma unroll
      for (int mt = 0; mt < 4; ++mt)
        af[mt] = lds_frag(As, wm * 64 + mt * 16 + l16, kk * 4 + quad);
#pragma unroll
      for (int nt = 0; nt < 4; ++nt) {
        b1[nt]  = lds_frag(Bs1, wn * 64 + nt * 16 + l16, kk * 4 + quad);
        b2v[nt] = lds_frag(Bs2, wn * 64 + nt * 16 + l16, kk * 4 + quad);
      }
#pragma unroll
      for (int mt = 0; mt < 4; ++mt)
#pragma unroll
        for (int nt = 0; nt < 4; ++nt) {
          acc1[mt][nt] = __builtin_amdgcn_mfma_f32_16x16x32_bf16(af[mt], b1[nt],  acc1[mt][nt], 0, 0, 0);
          acc2[mt][nt] = __builtin_amdgcn_mfma_f32_16x16x32_bf16(af[mt], b2v[nt], acc2[mt][nt], 0, 0, 0);
        }
    }
    __syncthreads();
  }
#pragma unroll
  for (int mt = 0; mt < 4; ++mt)
#pragma unroll
    for (int nt = 0; nt < 4; ++nt)
#pragma unroll
      for (int r = 0; r < 4; ++r) {
        int tl = wm * 64 + mt * 16 + quad * 4 + r;
        int sl = wn * 64 + nt * 16 + l16;
        float pv = pis[tl];
        float v = (n0 + sl <= m0 + tl) ? (pv * acc1[mt][nt][r] + (1.f - pv) * acc2[mt][nt][r]) : 0.f;
        Sh[tl * 136 + sl] = f2b(v);
      }
  __syncthreads();
  int c = tid & 15, g = tid >> 4;
#pragma unroll
  for (int j = 0; j < 8; ++j) {
    int r = j * 16 + g;
    size_t gb = (size_t)p * 65536 + (size_t)(m0 + r) * 256 + n0 + c * 8;
    *(short8*)(S + gb) = *(const short8*)(Sh + r * 136 + c * 8);
  }
}

// =====================================================================
// K4: O = SCALE * S @ V -> LO; full-line stores.  grid (1,2,512)
// =====================================================================
__global__ __launch_bounds__(256, 4) void pv_kernel(const unsigned short* __restrict__ S,
                                                    const unsigned short* __restrict__ Vt,
                                                    unsigned short* __restrict__ LO) {
  __shared__ alignas(16) unsigned short Sh[17408];
  unsigned short* As = Sh;
  unsigned short* Bs = Sh + 8192;
  int p = blockIdx.z;
  int b = p >> 3, hh = p & 7;
  int tid = threadIdx.x;
  int lane = tid & 63, wid = tid >> 6;
  int wm = wid >> 1, wn = wid & 1;
  int quad = lane >> 4, l16 = lane & 15;
  int m0 = blockIdx.y * 128;
  int kEnd = (blockIdx.y == 0) ? 128 : 256;
  const unsigned short* Ab = S  + (size_t)p * 65536 + (size_t)m0 * 256;
  const unsigned short* Bb = Vt + (size_t)p * 32768;

  floatx4 acc[4][4];
#pragma unroll
  for (int i = 0; i < 4; ++i)
#pragma unroll
    for (int j = 0; j < 4; ++j)
#pragma unroll
      for (int r = 0; r < 4; ++r) acc[i][j][r] = 0.f;

  for (int kt = 0; kt < kEnd; kt += 64) {
    stage_async(Ab + kt, 256, As, tid);
    stage_async(Bb + kt, 256, Bs, tid);
    __syncthreads();
#pragma unroll
    for (int kk = 0; kk < 2; ++kk) {
      short8 af[4], bfv[4];
#pragma unroll
      for (int mt = 0; mt < 4; ++mt)
        af[mt] = lds_frag(As, wm * 64 + mt * 16 + l16, kk * 4 + quad);
#pragma unroll
      for (int nt = 0; nt < 4; ++nt)
        bfv[nt] = lds_frag(Bs, wn * 64 + nt * 16 + l16, kk * 4 + quad);
#pragma unroll
      for (int mt = 0; mt < 4; ++mt)
#pragma unroll
        for (int nt = 0; nt < 4; ++nt)
          acc[mt][nt] = __builtin_amdgcn_mfma_f32_16x16x32_bf16(af[mt], bfv[nt], acc[mt][nt], 0, 0, 0);
    }
    __syncthreads();
  }
#pragma unroll
  for (int mt = 0; mt < 4; ++mt)
#pragma unroll
    for (int nt = 0; nt < 4; ++nt)
#pragma unroll
      for (int r = 0; r < 4; ++r) {
        int tl = wm * 64 + mt * 16 + quad * 4 + r;
        int d = wn * 64 + nt * 16 + l16;
        Sh[tl * 136 + d] = f2b(SCALE_ * acc[mt][nt][r]);
      }
  __syncthreads();
  int c = tid & 15, g = tid >> 4;
#pragma unroll
  for (int j = 0; j < 8; ++j) {
    int r = j * 16 + g;
    int t = m0 + r;
    size_t gb = ((size_t)t * 64 + b) * 1024 + hh * 128 + c * 8;
    *(short8*)(LO + gb) = *(const short8*)(Sh + r * 136 + c * 8);
  }
}

// =====================================================================
// K5: attn_out = LO @ Wo^T (bf16 out) — 256x256 4-phase dbuf, 1 round.
// =====================================================================
__global__ __launch_bounds__(512, 1) void wo_gemm(const unsigned short* __restrict__ A,
                                                  const unsigned short* __restrict__ B,
                                                  unsigned short* __restrict__ attn) {
  __shared__ alignas(16) unsigned short Sh[65536];
  int tid = threadIdx.x;
  int lane = tid & 63, wid = tid >> 6;
  int wm = wid >> 2, wn = wid & 3;
  int quad = lane >> 4, l16 = lane & 15;
  int s7 = l16 & 7;

  int bid = blockIdx.y * 4 + blockIdx.x;
  int swz = (bid & 7) * 32 + (bid >> 3);
  int bx = swz & 3, by = swz >> 2;
  int n0 = bx * 256, m0 = by * 256;

  const unsigned short* AbP = A + (size_t)m0 * DM_;
  const unsigned short* AbHP = AbP + (size_t)128 * DM_;
  const unsigned short* BbP = B + (size_t)n0 * DM_;
  const unsigned short* BbHP = BbP + (size_t)128 * DM_;

  int r0 = tid >> 3, jj = tid & 7;
  int cg = jj ^ (r0 & 7);
  size_t oA0 = (size_t)r0 * DM_ + cg * 8;
  size_t oA1 = (size_t)(r0 + 64) * DM_ + cg * 8;
  size_t oB0 = oA0, oB1 = oA1;
  int lo0 = tid * 8, lo1 = 4096 + tid * 8;

  floatx4 acc[8][4];
#pragma unroll
  for (int i = 0; i < 8; ++i)
#pragma unroll
    for (int j = 0; j < 4; ++j)
#pragma unroll
      for (int r = 0; r < 4; ++r) acc[i][j][r] = 0.f;

  stage_h(AbP,        oA0, oA1, Sh,         lo0, lo1);
  stage_h(AbHP,       oA0, oA1, Sh + 8192,  lo0, lo1);
  stage_h(BbP,        oB0, oB1, Sh + 16384, lo0, lo1);
  stage_h(BbHP,       oB0, oB1, Sh + 24576, lo0, lo1);
  stage_h(AbP + 64,   oA0, oA1, Sh + 32768, lo0, lo1);
  stage_h(AbHP + 64,  oA0, oA1, Sh + 40960, lo0, lo1);
  asm volatile("s_waitcnt vmcnt(4)" ::: "memory");
  __builtin_amdgcn_s_barrier();

  for (int t = 0; t < 16; t += 2) {
    TILE_BODY(t,     Sh,         Sh + 32768)
    TILE_BODY(t + 1, Sh + 32768, Sh)
  }

  __syncthreads();
#pragma unroll
  for (int hq = 0; hq < 2; ++hq) {
    if ((wn >> 1) == hq) {
#pragma unroll
      for (int mt = 0; mt < 8; ++mt)
#pragma unroll
        for (int nt = 0; nt < 4; ++nt)
#pragma unroll
          for (int r = 0; r < 4; ++r) {
            int row = wm * 128 + mt * 16 + quad * 4 + r;
            int col = (wn & 1) * 64 + nt * 16 + l16;
            Sh[row * 136 + col] = f2b(acc[mt][nt][r]);
          }
    }
    __syncthreads();
    int c = tid & 15, g = tid >> 4;
#pragma unroll
    for (int j = 0; j < 8; ++j) {
      int row = j * 32 + g;
      *(short8*)(attn + (size_t)(m0 + row) * DM_ + n0 + hq * 128 + c * 8) =
          *(const short8*)(Sh + row * 136 + c * 8);
    }
    __syncthreads();
  }
}

// =====================================================================
// K6: fused residual + LayerNorm: out = LN(h + attn_bf16).  1 block/row.
// =====================================================================
__global__ __launch_bounds__(256) void ln_res(const unsigned short* __restrict__ attn,
                                              const float* __restrict__ hin,
                                              const float* __restrict__ gamma,
                                              const float* __restrict__ beta,
                                              float* __restrict__ out) {
  int row = blockIdx.x;
  int tid = threadIdx.x;
  const unsigned short* ap = attn + (size_t)row * DM_ + tid * 4;
  const float* hp = hin + (size_t)row * DM_ + tid * 4;
  short4v av = *(const short4v*)ap;
  float4 hv = *(const float4*)hp;
  float x[4];
  x[0] = hv.x + b2f((unsigned short)av[0]);
  x[1] = hv.y + b2f((unsigned short)av[1]);
  x[2] = hv.z + b2f((unsigned short)av[2]);
  x[3] = hv.w + b2f((unsigned short)av[3]);
  float s  = x[0] + x[1] + x[2] + x[3];
  float ss = x[0] * x[0] + x[1] * x[1] + x[2] * x[2] + x[3] * x[3];
#pragma unroll
  for (int off = 32; off; off >>= 1) {
    s  += __shfl_down(s, off);
    ss += __shfl_down(ss, off);
  }
  __shared__ float rs[4], rss[4];
  int wv = tid >> 6, lane = tid & 63;
  if (lane == 0) { rs[wv] = s; rss[wv] = ss; }
  __syncthreads();
  float St  = rs[0] + rs[1] + rs[2] + rs[3];
  float SSt = rss[0] + rss[1] + rss[2] + rss[3];
  float mu = St * (1.f / DM_);
  float var = SSt * (1.f / DM_) - mu * mu;
  float rstd = rsqrtf(var + LN_EPS_);
  float4 o;
#pragma unroll
  for (int j = 0; j < 4; ++j) {
    int c = tid * 4 + j;
    (&o.x)[j] = gamma[c] * (x[j] - mu) * rstd + beta[c];
  }
  *(float4*)(out + (size_t)row * DM_ + tid * 4) = o;
}

// =====================================================================
extern "C" void kernel_launch(void* const* d_in, const int* in_sizes, int n_in,
                              void* d_out, int out_size, void* d_ws, size_t ws_size,
                              hipStream_t stream) {
  const float* h     = (const float*)d_in[0];
  const float* Wqkv  = (const float*)d_in[1];
  const float* Wo    = (const float*)d_in[2];
  const float* pi0   = (const float*)d_in[3];
  const float* gamma = (const float*)d_in[4];
  const float* beta  = (const float*)d_in[5];
  char* ws = (char*)d_ws;

  unsigned short* QKV   = (unsigned short*)ws;
  unsigned short* Sbuf  = (unsigned short*)(ws + 134217728ull);
  unsigned short* hb    = (unsigned short*)(ws + 134217728ull);   // dead after qkv_gemm
  unsigned short* Wqkvb = (unsigned short*)(ws + 167772160ull);   // dead after qkv_gemm
  unsigned short* Wob   = (unsigned short*)(ws + 201326592ull);
  unsigned short* LO    = (unsigned short*)ws;                    // overwrites q-part (dead)
  unsigned short* attn  = (unsigned short*)(ws + 134217728ull);   // overwrites Sbuf (dead after pv)
  float* X = (float*)d_out;

  dim3 blk(256);
  cvt_all<<<dim3(10752), blk, 0, stream>>>(h, Wqkv, Wo, hb, Wqkvb, Wob);
  qkv_gemm<<<dim3(16, 64, 1), dim3(1024), 0, stream>>>(hb, Wqkvb, QKV);
  scores_kernel<<<dim3(3, 1, PAIRS_), blk, 0, stream>>>(QKV, pi0, Sbuf);
  pv_kernel<<<dim3(1, 2, PAIRS_), blk, 0, stream>>>(Sbuf, QKV + (size_t)3 * 16777216, LO);
  wo_gemm<<<dim3(4, 64, 1), dim3(512), 0, stream>>>(LO, Wob, attn);
  ln_res<<<dim3(ROWS_, 1, 1), blk, 0, stream>>>(attn, h, gamma, beta, X);
}

// Round 9
// 418.508 us; speedup vs baseline: 1.1903x; 1.0028x over previous
//
#include <hip/hip_runtime.h>

// ---- problem constants ----
#define H_     8
#define DM_    1024
#define NQKV_  4096
#define ROWS_  16384          // SLEN*BSZ = 256*64
#define PAIRS_ 512            // BSZ*H
#define SCALE_ 0.08838834764831845f
#define LN_EPS_ 1e-5f

typedef __attribute__((ext_vector_type(8))) short short8;   // 8 bf16 (4 VGPRs)
typedef __attribute__((ext_vector_type(4))) short short4v;  // 4 bf16
typedef __attribute__((ext_vector_type(4))) float floatx4;  // MFMA accumulator

__device__ __forceinline__ float b2f(unsigned short u) {
  union { unsigned int i; float f; } v; v.i = ((unsigned int)u) << 16; return v.f;
}
__device__ __forceinline__ unsigned short f2b(float f) {
  union { unsigned int i; float f; } v; v.f = f;
  unsigned int b = v.i;
  b += 0x7FFFu + ((b >> 16) & 1u);   // round-to-nearest-even
  return (unsigned short)(b >> 16);
}

__device__ __forceinline__ void gl_lds(const unsigned short* g, unsigned short* s) {
  __builtin_amdgcn_global_load_lds(
      (const __attribute__((address_space(1))) unsigned int*)g,
      (__attribute__((address_space(3))) unsigned int*)s, 16, 0, 0);
}

// ---- async stage with XOR bank swizzle (256 threads, 128x64 tile) ----
__device__ __forceinline__ void stage_async(const unsigned short* __restrict__ g,
                                            size_t ld, unsigned short* s, int tid) {
#pragma unroll
  for (int p = 0; p < 4; ++p) {
    int idx = p * 256 + tid;
    int r = idx >> 3, j = idx & 7;
    int cg = j ^ (r & 7);
    gl_lds(g + (size_t)r * ld + cg * 8, s + (size_t)idx * 8);
  }
}
__device__ __forceinline__ short8 lds_frag(const unsigned short* s, int row, int cg) {
  return *(const short8*)(s + row * 64 + ((cg ^ (row & 7)) << 3));
}

// =====================================================================
// K0: fused fp32 -> bf16 convert of h, Wqkv, Wo (8 elems/thread)
// =====================================================================
__global__ __launch_bounds__(256) void cvt_all(const float* __restrict__ h,
                                               const float* __restrict__ wq,
                                               const float* __restrict__ wo,
                                               unsigned short* __restrict__ hb,
                                               unsigned short* __restrict__ wqb,
                                               unsigned short* __restrict__ wob) {
  int i = blockIdx.x * 256 + threadIdx.x;
  const float* src; unsigned short* dst; int off;
  if (i < 2097152)      { src = h;  dst = hb;  off = i; }
  else if (i < 2621440) { src = wq; dst = wqb; off = i - 2097152; }
  else                  { src = wo; dst = wob; off = i - 2621440; }
  const float4* s4 = (const float4*)(src + (size_t)off * 8);
  float4 v0 = s4[0], v1 = s4[1];
  union { short8 v; unsigned short u[8]; } pk;
  pk.u[0] = f2b(v0.x); pk.u[1] = f2b(v0.y); pk.u[2] = f2b(v0.z); pk.u[3] = f2b(v0.w);
  pk.u[4] = f2b(v1.x); pk.u[5] = f2b(v1.y); pk.u[6] = f2b(v1.z); pk.u[7] = f2b(v1.w);
  *(short8*)(dst + (size_t)off * 8) = pk.v;
}

// =====================================================================
// K1: qkv gemm, 256x256 tile, 1024 threads = 16 waves (4M x 4N),
//   acc[4][4] = 64 AGPR, ~128 regs/wave -> 16 waves/CU (register-file
//   ceiling: 512 regs/lane / 128 = 4 waves/SIMD).  Round-8 measured:
//   161us, 853 TF, Occ 43%, FETCH 147MB.  FROZEN — structural optimum
//   for this decomposition (smaller tiles blow HBM traffic r4/r7;
//   bigger acc halves occupancy r2/r6).
// =====================================================================
__global__ __launch_bounds__(1024, 4) void qkv_gemm(const unsigned short* __restrict__ A,
                                                    const unsigned short* __restrict__ B,
                                                    unsigned short* __restrict__ QKV) {
  __shared__ alignas(16) unsigned short Sh[65536];   // 2 bufs x (A 32KB | B 32KB)
  int tid = threadIdx.x;
  int lane = tid & 63, wid = tid >> 6;
  int wm = wid >> 2, wn = wid & 3;          // 4M x 4N wave grid, wave owns 64x64
  int quad = lane >> 4, l16 = lane & 15;
  int s7 = l16 & 7;

  // XCD-contiguous block swizzle (1024 blocks, bijective: 8 x 128)
  int bid = blockIdx.y * 16 + blockIdx.x;
  int swz = (bid & 7) * 128 + (bid >> 3);
  int bx = swz & 15, by = swz >> 4;
  int n0 = bx * 256, hh = bx >> 1, part0 = (bx & 1) * 2, bb = by;

  const unsigned short* AbP = A + (size_t)bb * DM_;   // row l at AbP + l*lda
  const size_t lda = (size_t)64 * DM_;
  const unsigned short* BbP = B + (size_t)n0 * DM_;

  // stage offsets: idx = p*1024 + tid, r = (tid>>3) + p*128, j = tid&7
  int r0 = tid >> 3, jj = tid & 7;
  int cg = jj ^ (r0 & 7);
  size_t oA = (size_t)r0 * lda + cg * 8;    // + p*128*lda
  size_t oB = (size_t)r0 * DM_ + cg * 8;    // + p*128*DM_
  int lo = tid * 8;                          // + p*8192

  floatx4 acc[4][4];
#pragma unroll
  for (int i = 0; i < 4; ++i)
#pragma unroll
    for (int j = 0; j < 4; ++j)
#pragma unroll
      for (int r = 0; r < 4; ++r) acc[i][j][r] = 0.f;

#define QSTAGE(KT, SA)                                                         \
  gl_lds(AbP + (KT) + oA,                     (SA) + lo);                      \
  gl_lds(AbP + (KT) + oA + (size_t)128 * lda, (SA) + 8192 + lo);               \
  gl_lds(BbP + (KT) + oB,                     (SA) + 16384 + lo);              \
  gl_lds(BbP + (KT) + oB + (size_t)128 * DM_, (SA) + 24576 + lo);

  QSTAGE(0, Sh)

  for (int t = 0; t < 16; ++t) {
    unsigned short* SA = Sh + (t & 1) * 32768;
    if (t < 15) { QSTAGE((size_t)(t + 1) * 64, Sh + ((t + 1) & 1) * 32768) }
    if (t < 15) { asm volatile("s_waitcnt vmcnt(4)" ::: "memory"); }   // tile t resident; t+1 in flight
    else        { asm volatile("s_waitcnt vmcnt(0)" ::: "memory"); }
    __builtin_amdgcn_s_barrier();
    const unsigned short* aB0 = SA + (wm * 64 + l16) * 64 + ((quad ^ s7) << 3);
    const unsigned short* aB1 = SA + (wm * 64 + l16) * 64 + (((4 + quad) ^ s7) << 3);
    const unsigned short* bB0 = SA + 16384 + (wn * 64 + l16) * 64 + ((quad ^ s7) << 3);
    const unsigned short* bB1 = SA + 16384 + (wn * 64 + l16) * 64 + (((4 + quad) ^ s7) << 3);
    short8 a[4], b[4];
    // kk = 0
#pragma unroll
    for (int mt = 0; mt < 4; ++mt) a[mt] = *(const short8*)(aB0 + mt * 1024);
#pragma unroll
    for (int nt = 0; nt < 4; ++nt) b[nt] = *(const short8*)(bB0 + nt * 1024);
#pragma unroll
    for (int mt = 0; mt < 4; ++mt)
#pragma unroll
      for (int nt = 0; nt < 4; ++nt)
        acc[mt][nt] = __builtin_amdgcn_mfma_f32_16x16x32_bf16(a[mt], b[nt], acc[mt][nt], 0, 0, 0);
    // kk = 1
#pragma unroll
    for (int mt = 0; mt < 4; ++mt) a[mt] = *(const short8*)(aB1 + mt * 1024);
#pragma unroll
    for (int nt = 0; nt < 4; ++nt) b[nt] = *(const short8*)(bB1 + nt * 1024);
#pragma unroll
    for (int mt = 0; mt < 4; ++mt)
#pragma unroll
      for (int nt = 0; nt < 4; ++nt)
        acc[mt][nt] = __builtin_amdgcn_mfma_f32_16x16x32_bf16(a[mt], b[nt], acc[mt][nt], 0, 0, 0);
    __builtin_amdgcn_s_barrier();          // reads of tile t retired in all waves
  }
#undef QSTAGE

  // ================= epilogue =================
  int c16 = tid & 15, g64 = tid >> 4;      // 0..15 / 0..63
  bool isV = (part0 + (wn >> 1)) == 3;
  float* Pf = (float*)Sh;                  // [256][4] partial row-sums = 4KB
  float rsum[4][4], inv[4][4];
  if (!isV) {
#pragma unroll
    for (int mt = 0; mt < 4; ++mt)
#pragma unroll
      for (int r = 0; r < 4; ++r) rsum[mt][r] = 0.f;
#pragma unroll
    for (int mt = 0; mt < 4; ++mt)
#pragma unroll
      for (int nt = 0; nt < 4; ++nt)
#pragma unroll
        for (int r = 0; r < 4; ++r) {
          float x = acc[mt][nt][r];
          float f = x > 0.f ? x + 1.f : __expf(x);
          acc[mt][nt][r] = f;
          rsum[mt][r] += f;
        }
#pragma unroll
    for (int off = 1; off < 16; off <<= 1)
#pragma unroll
      for (int mt = 0; mt < 4; ++mt)
#pragma unroll
        for (int r = 0; r < 4; ++r)
          rsum[mt][r] += __shfl_xor(rsum[mt][r], off);
    if (l16 == 0) {
#pragma unroll
      for (int mt = 0; mt < 4; ++mt)
#pragma unroll
        for (int r = 0; r < 4; ++r)
          Pf[(wm * 64 + mt * 16 + quad * 4 + r) * 4 + wn] = rsum[mt][r];
    }
  }
  __syncthreads();
  if (!isV) {
#pragma unroll
    for (int mt = 0; mt < 4; ++mt)
#pragma unroll
      for (int r = 0; r < 4; ++r)
        inv[mt][r] = 1.f / (rsum[mt][r] + Pf[(wm * 64 + mt * 16 + quad * 4 + r) * 4 + (wn ^ 1)]);
  }
  __syncthreads();

  // two 128-col parts, staged+stored sequentially through LDS
#pragma unroll
  for (int hq = 0; hq < 2; ++hq) {
    int part = part0 + hq;
    if ((wn >> 1) == hq) {
      if (part < 3) {
        // phi-normalized P: T[256][136]
#pragma unroll
        for (int mt = 0; mt < 4; ++mt)
#pragma unroll
          for (int nt = 0; nt < 4; ++nt)
#pragma unroll
            for (int r = 0; r < 4; ++r) {
              int row = wm * 64 + mt * 16 + quad * 4 + r;
              int col = (wn & 1) * 64 + nt * 16 + l16;
              Sh[row * 136 + col] = f2b(acc[mt][nt][r] * inv[mt][r]);
            }
      } else {
        // V transpose: T[128][264] = [d][l]
#pragma unroll
        for (int mt = 0; mt < 4; ++mt)
#pragma unroll
          for (int nt = 0; nt < 4; ++nt)
#pragma unroll
            for (int r = 0; r < 4; ++r) {
              int d = (wn & 1) * 64 + nt * 16 + l16;
              int l = wm * 64 + mt * 16 + quad * 4 + r;
              Sh[d * 264 + l] = f2b(acc[mt][nt][r]);
            }
      }
    }
    __syncthreads();
    if (part < 3) {
      unsigned short* P = QKV + (size_t)part * 16777216 + (size_t)(bb * 8 + hh) * 32768;
#pragma unroll
      for (int j = 0; j < 4; ++j) {
        int row = j * 64 + g64;
        *(short8*)(P + (size_t)row * 128 + c16 * 8) = *(const short8*)(Sh + row * 136 + c16 * 8);
      }
    } else {
      unsigned short* Vt = QKV + (size_t)3 * 16777216 + (size_t)(bb * 8 + hh) * 32768;
      int cg2 = tid & 31, g32 = tid >> 5;
#pragma unroll
      for (int j = 0; j < 4; ++j) {
        int d = j * 32 + g32;
        *(short8*)(Vt + (size_t)d * 256 + cg2 * 8) = *(const short8*)(Sh + d * 264 + cg2 * 8);
      }
    }
    __syncthreads();
  }
}

// =====================================================================
// K3: combined masked scores.  grid (3, 1, 512); full-line S stores.
// =====================================================================
__global__ __launch_bounds__(256) void scores_kernel(const unsigned short* __restrict__ QKV,
                                                     const float* __restrict__ pi0,
                                                     unsigned short* __restrict__ S) {
  __shared__ alignas(16) unsigned short Sh[24576];
  __shared__ float pis[128];
  unsigned short* As  = Sh;
  unsigned short* Bs1 = Sh + 8192;
  unsigned short* Bs2 = Sh + 16384;
  int p = blockIdx.z;
  int hh = p & 7;
  int tid = threadIdx.x;
  int lane = tid & 63, wid = tid >> 6;
  int wm = wid >> 1, wn = wid & 1;
  int quad = lane >> 4, l16 = lane & 15;
  int tix = blockIdx.x;
  int m0 = (tix >= 1) ? 128 : 0;
  int n0 = (tix == 2) ? 128 : 0;
  if (tid < 128) {
    float pv = pi0[hh * 256 + m0 + tid];
    pis[tid] = fminf(fmaxf(pv, 0.f), 1.f);
  }
  const unsigned short* Qb  = QKV + (size_t)p * 32768 + (size_t)m0 * 128;
  const unsigned short* K1b = QKV + 16777216     + (size_t)p * 32768 + (size_t)n0 * 128;
  const unsigned short* K2b = QKV + 2 * 16777216 + (size_t)p * 32768 + (size_t)n0 * 128;

  floatx4 acc1[4][4], acc2[4][4];
#pragma unroll
  for (int i = 0; i < 4; ++i)
#pragma unroll
    for (int j = 0; j < 4; ++j)
#pragma unroll
      for (int r = 0; r < 4; ++r) { acc1[i][j][r] = 0.f; acc2[i][j][r] = 0.f; }

  for (int kt = 0; kt < 128; kt += 64) {
    stage_async(Qb + kt, 128, As, tid);
    stage_async(K1b + kt, 128, Bs1, tid);
    stage_async(K2b + kt, 128, Bs2, tid);
    __syncthreads();
#pragma unroll
    for (int kk = 0; kk < 2; ++kk) {
      short8 af[4], b1[4], b2v[4];
#pragma unroll
      for (int mt = 0; mt < 4; ++mt)
        af[mt] = lds_frag(As, wm * 64 + mt * 16 + l16, kk * 4 + quad);
#pragma unroll
      for (int nt = 0; nt < 4; ++nt) {
        b1[nt]  = lds_frag(Bs1, wn * 64 + nt * 16 + l16, kk * 4 + quad);
        b2v[nt] = lds_frag(Bs2, wn * 64 + nt * 16 + l16, kk * 4 + quad);
      }
#pragma unroll
      for (int mt = 0; mt < 4; ++mt)
#pragma unroll
        for (int nt = 0; nt < 4; ++nt) {
          acc1[mt][nt] = __builtin_amdgcn_mfma_f32_16x16x32_bf16(af[mt], b1[nt],  acc1[mt][nt], 0, 0, 0);
          acc2[mt][nt] = __builtin_amdgcn_mfma_f32_16x16x32_bf16(af[mt], b2v[nt], acc2[mt][nt], 0, 0, 0);
        }
    }
    __syncthreads();
  }
#pragma unroll
  for (int mt = 0; mt < 4; ++mt)
#pragma unroll
    for (int nt = 0; nt < 4; ++nt)
#pragma unroll
      for (int r = 0; r < 4; ++r) {
        int tl = wm * 64 + mt * 16 + quad * 4 + r;
        int sl = wn * 64 + nt * 16 + l16;
        float pv = pis[tl];
        float v = (n0 + sl <= m0 + tl) ? (pv * acc1[mt][nt][r] + (1.f - pv) * acc2[mt][nt][r]) : 0.f;
        Sh[tl * 136 + sl] = f2b(v);
      }
  __syncthreads();
  int c = tid & 15, g = tid >> 4;
#pragma unroll
  for (int j = 0; j < 8; ++j) {
    int r = j * 16 + g;
    size_t gb = (size_t)p * 65536 + (size_t)(m0 + r) * 256 + n0 + c * 8;
    *(short8*)(S + gb) = *(const short8*)(Sh + r * 136 + c * 8);
  }
}

// =====================================================================
// K4: O = SCALE * S @ V -> LO; full-line stores.  grid (1,2,512)
// =====================================================================
__global__ __launch_bounds__(256, 4) void pv_kernel(const unsigned short* __restrict__ S,
                                                    const unsigned short* __restrict__ Vt,
                                                    unsigned short* __restrict__ LO) {
  __shared__ alignas(16) unsigned short Sh[17408];
  unsigned short* As = Sh;
  unsigned short* Bs = Sh + 8192;
  int p = blockIdx.z;
  int b = p >> 3, hh = p & 7;
  int tid = threadIdx.x;
  int lane = tid & 63, wid = tid >> 6;
  int wm = wid >> 1, wn = wid & 1;
  int quad = lane >> 4, l16 = lane & 15;
  int m0 = blockIdx.y * 128;
  int kEnd = (blockIdx.y == 0) ? 128 : 256;
  const unsigned short* Ab = S  + (size_t)p * 65536 + (size_t)m0 * 256;
  const unsigned short* Bb = Vt + (size_t)p * 32768;

  floatx4 acc[4][4];
#pragma unroll
  for (int i = 0; i < 4; ++i)
#pragma unroll
    for (int j = 0; j < 4; ++j)
#pragma unroll
      for (int r = 0; r < 4; ++r) acc[i][j][r] = 0.f;

  for (int kt = 0; kt < kEnd; kt += 64) {
    stage_async(Ab + kt, 256, As, tid);
    stage_async(Bb + kt, 256, Bs, tid);
    __syncthreads();
#pragma unroll
    for (int kk = 0; kk < 2; ++kk) {
      short8 af[4], bfv[4];
#pragma unroll
      for (int mt = 0; mt < 4; ++mt)
        af[mt] = lds_frag(As, wm * 64 + mt * 16 + l16, kk * 4 + quad);
#pragma unroll
      for (int nt = 0; nt < 4; ++nt)
        bfv[nt] = lds_frag(Bs, wn * 64 + nt * 16 + l16, kk * 4 + quad);
#pragma unroll
      for (int mt = 0; mt < 4; ++mt)
#pragma unroll
        for (int nt = 0; nt < 4; ++nt)
          acc[mt][nt] = __builtin_amdgcn_mfma_f32_16x16x32_bf16(af[mt], bfv[nt], acc[mt][nt], 0, 0, 0);
    }
    __syncthreads();
  }
#pragma unroll
  for (int mt = 0; mt < 4; ++mt)
#pragma unroll
    for (int nt = 0; nt < 4; ++nt)
#pragma unroll
      for (int r = 0; r < 4; ++r) {
        int tl = wm * 64 + mt * 16 + quad * 4 + r;
        int d = wn * 64 + nt * 16 + l16;
        Sh[tl * 136 + d] = f2b(SCALE_ * acc[mt][nt][r]);
      }
  __syncthreads();
  int c = tid & 15, g = tid >> 4;
#pragma unroll
  for (int j = 0; j < 8; ++j) {
    int r = j * 16 + g;
    int t = m0 + r;
    size_t gb = ((size_t)t * 64 + b) * 1024 + hh * 128 + c * 8;
    *(short8*)(LO + gb) = *(const short8*)(Sh + r * 136 + c * 8);
  }
}

// =====================================================================
// K5: attn_out = LO @ Wo^T (bf16 out) — ported to the round-8 qkv
//   structure: 1024 threads, 16 waves 4M x 4N, acc[4][4], dbuf 128KB,
//   counted vmcnt(4).  grid (4,64) = 256 blocks = 1 block/CU, 1 round.
// =====================================================================
__global__ __launch_bounds__(1024, 4) void wo_gemm(const unsigned short* __restrict__ A,
                                                   const unsigned short* __restrict__ B,
                                                   unsigned short* __restrict__ attn) {
  __shared__ alignas(16) unsigned short Sh[65536];   // 2 bufs x (A 32KB | B 32KB)
  int tid = threadIdx.x;
  int lane = tid & 63, wid = tid >> 6;
  int wm = wid >> 2, wn = wid & 3;          // 4M x 4N, wave owns 64x64
  int quad = lane >> 4, l16 = lane & 15;
  int s7 = l16 & 7;

  // 256 blocks, bijective XCD swizzle 8 x 32
  int bid = blockIdx.y * 4 + blockIdx.x;
  int swz = (bid & 7) * 32 + (bid >> 3);
  int bx = swz & 3, by = swz >> 2;
  int n0 = bx * 256, m0 = by * 256;

  const unsigned short* AbP = A + (size_t)m0 * DM_;
  const unsigned short* BbP = B + (size_t)n0 * DM_;

  int r0 = tid >> 3, jj = tid & 7;
  int cg = jj ^ (r0 & 7);
  size_t oA = (size_t)r0 * DM_ + cg * 8;    // + p*128*DM_
  int lo = tid * 8;                          // + p*8192

  floatx4 acc[4][4];
#pragma unroll
  for (int i = 0; i < 4; ++i)
#pragma unroll
    for (int j = 0; j < 4; ++j)
#pragma unroll
      for (int r = 0; r < 4; ++r) acc[i][j][r] = 0.f;

#define WSTAGE(KT, SA)                                                         \
  gl_lds(AbP + (KT) + oA,                     (SA) + lo);                      \
  gl_lds(AbP + (KT) + oA + (size_t)128 * DM_, (SA) + 8192 + lo);               \
  gl_lds(BbP + (KT) + oA,                     (SA) + 16384 + lo);              \
  gl_lds(BbP + (KT) + oA + (size_t)128 * DM_, (SA) + 24576 + lo);

  WSTAGE(0, Sh)

  for (int t = 0; t < 16; ++t) {
    unsigned short* SA = Sh + (t & 1) * 32768;
    if (t < 15) { WSTAGE((size_t)(t + 1) * 64, Sh + ((t + 1) & 1) * 32768) }
    if (t < 15) { asm volatile("s_waitcnt vmcnt(4)" ::: "memory"); }
    else        { asm volatile("s_waitcnt vmcnt(0)" ::: "memory"); }
    __builtin_amdgcn_s_barrier();
    const unsigned short* aB0 = SA + (wm * 64 + l16) * 64 + ((quad ^ s7) << 3);
    const unsigned short* aB1 = SA + (wm * 64 + l16) * 64 + (((4 + quad) ^ s7) << 3);
    const unsigned short* bB0 = SA + 16384 + (wn * 64 + l16) * 64 + ((quad ^ s7) << 3);
    const unsigned short* bB1 = SA + 16384 + (wn * 64 + l16) * 64 + (((4 + quad) ^ s7) << 3);
    short8 a[4], b[4];
    // kk = 0
#pragma unroll
    for (int mt = 0; mt < 4; ++mt) a[mt] = *(const short8*)(aB0 + mt * 1024);
#pragma unroll
    for (int nt = 0; nt < 4; ++nt) b[nt] = *(const short8*)(bB0 + nt * 1024);
#pragma unroll
    for (int mt = 0; mt < 4; ++mt)
#pragma unroll
      for (int nt = 0; nt < 4; ++nt)
        acc[mt][nt] = __builtin_amdgcn_mfma_f32_16x16x32_bf16(a[mt], b[nt], acc[mt][nt], 0, 0, 0);
    // kk = 1
#pragma unroll
    for (int mt = 0; mt < 4; ++mt) a[mt] = *(const short8*)(aB1 + mt * 1024);
#pragma unroll
    for (int nt = 0; nt < 4; ++nt) b[nt] = *(const short8*)(bB1 + nt * 1024);
#pragma unroll
    for (int mt = 0; mt < 4; ++mt)
#pragma unroll
      for (int nt = 0; nt < 4; ++nt)
        acc[mt][nt] = __builtin_amdgcn_mfma_f32_16x16x32_bf16(a[mt], b[nt], acc[mt][nt], 0, 0, 0);
    __builtin_amdgcn_s_barrier();
  }
#undef WSTAGE

  // epilogue: bf16 stores via T[256][136], two 128-col halves
  __syncthreads();
  int c16 = tid & 15, g64 = tid >> 4;
#pragma unroll
  for (int hq = 0; hq < 2; ++hq) {
    if ((wn >> 1) == hq) {
#pragma unroll
      for (int mt = 0; mt < 4; ++mt)
#pragma unroll
        for (int nt = 0; nt < 4; ++nt)
#pragma unroll
          for (int r = 0; r < 4; ++r) {
            int row = wm * 64 + mt * 16 + quad * 4 + r;
            int col = (wn & 1) * 64 + nt * 16 + l16;
            Sh[row * 136 + col] = f2b(acc[mt][nt][r]);
          }
    }
    __syncthreads();
#pragma unroll
    for (int j = 0; j < 4; ++j) {
      int row = j * 64 + g64;
      *(short8*)(attn + (size_t)(m0 + row) * DM_ + n0 + hq * 128 + c16 * 8) =
          *(const short8*)(Sh + row * 136 + c16 * 8);
    }
    __syncthreads();
  }
}

// =====================================================================
// K6: fused residual + LayerNorm: out = LN(h + attn_bf16).  1 block/row.
// =====================================================================
__global__ __launch_bounds__(256) void ln_res(const unsigned short* __restrict__ attn,
                                              const float* __restrict__ hin,
                                              const float* __restrict__ gamma,
                                              const float* __restrict__ beta,
                                              float* __restrict__ out) {
  int row = blockIdx.x;
  int tid = threadIdx.x;
  const unsigned short* ap = attn + (size_t)row * DM_ + tid * 4;
  const float* hp = hin + (size_t)row * DM_ + tid * 4;
  short4v av = *(const short4v*)ap;
  float4 hv = *(const float4*)hp;
  float x[4];
  x[0] = hv.x + b2f((unsigned short)av[0]);
  x[1] = hv.y + b2f((unsigned short)av[1]);
  x[2] = hv.z + b2f((unsigned short)av[2]);
  x[3] = hv.w + b2f((unsigned short)av[3]);
  float s  = x[0] + x[1] + x[2] + x[3];
  float ss = x[0] * x[0] + x[1] * x[1] + x[2] * x[2] + x[3] * x[3];
#pragma unroll
  for (int off = 32; off; off >>= 1) {
    s  += __shfl_down(s, off);
    ss += __shfl_down(ss, off);
  }
  __shared__ float rs[4], rss[4];
  int wv = tid >> 6, lane = tid & 63;
  if (lane == 0) { rs[wv] = s; rss[wv] = ss; }
  __syncthreads();
  float St  = rs[0] + rs[1] + rs[2] + rs[3];
  float SSt = rss[0] + rss[1] + rss[2] + rss[3];
  float mu = St * (1.f / DM_);
  float var = SSt * (1.f / DM_) - mu * mu;
  float rstd = rsqrtf(var + LN_EPS_);
  float4 o;
#pragma unroll
  for (int j = 0; j < 4; ++j) {
    int c = tid * 4 + j;
    (&o.x)[j] = gamma[c] * (x[j] - mu) * rstd + beta[c];
  }
  *(float4*)(out + (size_t)row * DM_ + tid * 4) = o;
}

// =====================================================================
extern "C" void kernel_launch(void* const* d_in, const int* in_sizes, int n_in,
                              void* d_out, int out_size, void* d_ws, size_t ws_size,
                              hipStream_t stream) {
  const float* h     = (const float*)d_in[0];
  const float* Wqkv  = (const float*)d_in[1];
  const float* Wo    = (const float*)d_in[2];
  const float* pi0   = (const float*)d_in[3];
  const float* gamma = (const float*)d_in[4];
  const float* beta  = (const float*)d_in[5];
  char* ws = (char*)d_ws;

  unsigned short* QKV   = (unsigned short*)ws;
  unsigned short* Sbuf  = (unsigned short*)(ws + 134217728ull);
  unsigned short* hb    = (unsigned short*)(ws + 134217728ull);   // dead after qkv_gemm
  unsigned short* Wqkvb = (unsigned short*)(ws + 167772160ull);   // dead after qkv_gemm
  unsigned short* Wob   = (unsigned short*)(ws + 201326592ull);
  unsigned short* LO    = (unsigned short*)ws;                    // overwrites q-part (dead)
  unsigned short* attn  = (unsigned short*)(ws + 134217728ull);   // overwrites Sbuf (dead after pv)
  float* X = (float*)d_out;

  dim3 blk(256);
  cvt_all<<<dim3(10752), blk, 0, stream>>>(h, Wqkv, Wo, hb, Wqkvb, Wob);
  qkv_gemm<<<dim3(16, 64, 1), dim3(1024), 0, stream>>>(hb, Wqkvb, QKV);
  scores_kernel<<<dim3(3, 1, PAIRS_), blk, 0, stream>>>(QKV, pi0, Sbuf);
  pv_kernel<<<dim3(1, 2, PAIRS_), blk, 0, stream>>>(Sbuf, QKV + (size_t)3 * 16777216, LO);
  wo_gemm<<<dim3(4, 64, 1), dim3(1024), 0, stream>>>(LO, Wob, attn);
  ln_res<<<dim3(ROWS_, 1, 1), blk, 0, stream>>>(attn, h, gamma, beta, X);
}